// Round 5
// baseline (45.881 us; speedup 1.0000x reference)
//
#include <hip/hip_runtime.h>

// NeRF fused render: B rays x S samples, MLP 3->64(relu)->4(exp), alpha composite.
// R5: TRUE packed fp32 via inline-asm v_pk_fma_f32. LDS holds pre-splatted
// operands ({A,A,B,B} per (ray,h); {wc,wc} per (h,c)) so no swizzle/mov is
// needed -- one ds_read_b128 feeds two splat pairs directly.

typedef float v2f __attribute__((ext_vector_type(2)));
typedef float v4f __attribute__((ext_vector_type(4)));

constexpr int S_TOTAL = 128;
constexpr int TPR     = 16;            // threads (lanes) per ray
constexpr int SPT     = S_TOTAL / TPR; // 8 samples per thread
constexpr int BLOCK   = 256;
constexpr int RPB     = BLOCK / TPR;   // 16 rays per block
constexpr int H       = 64;

static __device__ __forceinline__ v2f pk_fma(v2f a, v2f b, v2f c) {
    v2f d;
    asm("v_pk_fma_f32 %0, %1, %2, %3" : "=v"(d) : "v"(a), "v"(b), "v"(c));
    return d;
}

__global__ __launch_bounds__(BLOCK, 6)
void nerf_fused(const float* __restrict__ origins,
                const float* __restrict__ directions,
                const float* __restrict__ nearp,
                const float* __restrict__ farp,
                const float* __restrict__ W1,   // [3][64]
                const float* __restrict__ b1,   // [64]
                const float* __restrict__ W2,   // [64][4]
                const float* __restrict__ b2,   // [4]
                float* __restrict__ out,        // [B][3]
                int B)
{
    // ABs4[r][h] = {A,A,B,B}; pad h-dim so 4 per-wave bcast addrs hit distinct banks
    __shared__ v4f ABs4[RPB][H + 1];
    __shared__ v4f W2s4[H][2];           // {w0,w0,w1,w1}, {w2,w2,w3,w3}
    __shared__ float b2s[4];

    const int tid  = threadIdx.x;
    const int ray0 = blockIdx.x * RPB;

    if (tid < H) {
        const float w0 = W2[tid * 4 + 0];
        const float w1 = W2[tid * 4 + 1];
        const float w2 = W2[tid * 4 + 2];
        const float w3 = W2[tid * 4 + 3];
        W2s4[tid][0] = (v4f){w0, w0, w1, w1};
        W2s4[tid][1] = (v4f){w2, w2, w3, w3};
    }
    if (tid < 4) b2s[tid] = b2[tid];

#pragma unroll
    for (int idx = tid; idx < RPB * H; idx += BLOCK) {
        const int r   = idx >> 6;        // / H
        const int h   = idx & (H - 1);
        const int ray = ray0 + r;
        const float o0 = origins[ray * 3 + 0];
        const float o1 = origins[ray * 3 + 1];
        const float o2 = origins[ray * 3 + 2];
        float d0 = directions[ray * 3 + 0];
        float d1 = directions[ray * 3 + 1];
        float d2 = directions[ray * 3 + 2];
        const float nrm  = sqrtf(d0 * d0 + d1 * d1 + d2 * d2);
        const float rinv = 1.0f / fmaxf(nrm, 1e-12f);
        d0 *= rinv; d1 *= rinv; d2 *= rinv;
        const float w0 = W1[0 * H + h];
        const float w1 = W1[1 * H + h];
        const float w2 = W1[2 * H + h];
        const float A = fmaf(o2, w2, fmaf(o1, w1, fmaf(o0, w0, b1[h])));
        const float Bc = fmaf(d2, w2, fmaf(d1, w1, d0 * w0));
        ABs4[r][h] = (v4f){A, A, Bc, Bc};
    }
    __syncthreads();

    const int sub  = tid & (TPR - 1);    // lane within ray group
    const int rloc = tid >> 4;           // local ray index (log2(TPR)=4)
    const int ray  = ray0 + rloc;

    const float nr    = nearp[0];
    const float fr    = farp[0];
    const float delta = (fr - nr) * (1.0f / (float)S_TOTAL);

    // sample-pair midpoints (named, not arrays)
    const float sbase = (float)(sub * SPT) + 0.5f;
    const v2f mp0 = (v2f){fmaf(sbase + 0.0f, delta, nr), fmaf(sbase + 1.0f, delta, nr)};
    const v2f mp1 = (v2f){fmaf(sbase + 2.0f, delta, nr), fmaf(sbase + 3.0f, delta, nr)};
    const v2f mp2 = (v2f){fmaf(sbase + 4.0f, delta, nr), fmaf(sbase + 5.0f, delta, nr)};
    const v2f mp3 = (v2f){fmaf(sbase + 6.0f, delta, nr), fmaf(sbase + 7.0f, delta, nr)};

    // acc[channel][pair] as named scalars
    const v2f bc0 = (v2f){b2s[0], b2s[0]};
    const v2f bc1 = (v2f){b2s[1], b2s[1]};
    const v2f bc2 = (v2f){b2s[2], b2s[2]};
    const v2f bc3 = (v2f){b2s[3], b2s[3]};
    v2f a0p0 = bc0, a0p1 = bc0, a0p2 = bc0, a0p3 = bc0;
    v2f a1p0 = bc1, a1p1 = bc1, a1p2 = bc1, a1p3 = bc1;
    v2f a2p0 = bc2, a2p1 = bc2, a2p2 = bc2, a2p3 = bc2;
    v2f a3p0 = bc3, a3p1 = bc3, a3p2 = bc3, a3p3 = bc3;

    const v2f vzero = (v2f){0.0f, 0.0f};

#pragma unroll 4
    for (int h = 0; h < H; ++h) {
        const v4f ab = ABs4[rloc][h];                 // {A,A,B,B} : 1x ds_read_b128
        const v4f wA = W2s4[h][0];                    // {w0,w0,w1,w1}
        const v4f wB = W2s4[h][1];                    // {w2,w2,w3,w3}
        const v2f aa = (v2f){ab.x, ab.y};
        const v2f bb = (v2f){ab.z, ab.w};
        const v2f w0 = (v2f){wA.x, wA.y};
        const v2f w1 = (v2f){wA.z, wA.w};
        const v2f w2 = (v2f){wB.x, wB.y};
        const v2f w3 = (v2f){wB.z, wB.w};

#define NERF_STEP(MP, A0, A1, A2, A3)                                         \
        {                                                                     \
            v2f hp = pk_fma(MP, bb, aa);                                      \
            hp = __builtin_elementwise_max(hp, vzero);  /* 2x v_max_f32 */    \
            A0 = pk_fma(hp, w0, A0);                                          \
            A1 = pk_fma(hp, w1, A1);                                          \
            A2 = pk_fma(hp, w2, A2);                                          \
            A3 = pk_fma(hp, w3, A3);                                          \
        }
        NERF_STEP(mp0, a0p0, a1p0, a2p0, a3p0)
        NERF_STEP(mp1, a0p1, a1p1, a2p1, a3p1)
        NERF_STEP(mp2, a0p2, a1p2, a2p2, a3p2)
        NERF_STEP(mp3, a0p3, a1p3, a2p3, a3p3)
#undef NERF_STEP
    }

    // local (in-order) composite over this lane's 8 samples
    float Tloc = 1.0f, orr = 0.0f, og = 0.0f, ob = 0.0f;
#define NERF_COMP1(CR, CG, CB, SG)                                            \
    {                                                                         \
        const float sig = __expf(SG);                                         \
        const float e   = __expf(-sig * delta);  /* = 1 - alpha */            \
        Tloc *= e;                                                            \
        const float w = Tloc * (1.0f - e);       /* T * alpha */              \
        orr = fmaf(w, __expf(CR), orr);                                       \
        og  = fmaf(w, __expf(CG), og);                                        \
        ob  = fmaf(w, __expf(CB), ob);                                        \
    }
    NERF_COMP1(a0p0.x, a1p0.x, a2p0.x, a3p0.x)
    NERF_COMP1(a0p0.y, a1p0.y, a2p0.y, a3p0.y)
    NERF_COMP1(a0p1.x, a1p1.x, a2p1.x, a3p1.x)
    NERF_COMP1(a0p1.y, a1p1.y, a2p1.y, a3p1.y)
    NERF_COMP1(a0p2.x, a1p2.x, a2p2.x, a3p2.x)
    NERF_COMP1(a0p2.y, a1p2.y, a2p2.y, a3p2.y)
    NERF_COMP1(a0p3.x, a1p3.x, a2p3.x, a3p3.x)
    NERF_COMP1(a0p3.y, a1p3.y, a2p3.y, a3p3.y)
#undef NERF_COMP1

    // stitch across the 16 lanes of this ray:
    // inclusive scan-product of Tloc, then exclusive prefix for scaling
    float scan = Tloc;
#pragma unroll
    for (int off = 1; off < TPR; off <<= 1) {
        const float v = __shfl_up(scan, off, TPR);
        if (sub >= off) scan *= v;
    }
    float pre = __shfl_up(scan, 1, TPR);
    if (sub == 0) pre = 1.0f;

    orr *= pre; og *= pre; ob *= pre;
#pragma unroll
    for (int off = TPR / 2; off > 0; off >>= 1) {
        orr += __shfl_down(orr, off, TPR);
        og  += __shfl_down(og,  off, TPR);
        ob  += __shfl_down(ob,  off, TPR);
    }

    if (sub == 0) {
        out[ray * 3 + 0] = orr;
        out[ray * 3 + 1] = og;
        out[ray * 3 + 2] = ob;
    }
}

extern "C" void kernel_launch(void* const* d_in, const int* in_sizes, int n_in,
                              void* d_out, int out_size, void* d_ws, size_t ws_size,
                              hipStream_t stream) {
    const float* origins    = (const float*)d_in[0];
    const float* directions = (const float*)d_in[1];
    const float* nearp      = (const float*)d_in[2];
    const float* farp       = (const float*)d_in[3];
    const float* W1         = (const float*)d_in[4];
    const float* b1         = (const float*)d_in[5];
    const float* W2         = (const float*)d_in[6];
    const float* b2         = (const float*)d_in[7];
    float* out              = (float*)d_out;

    const int B     = in_sizes[0] / 3;       // 32768
    const int total = B * TPR;
    const int grid  = (total + BLOCK - 1) / BLOCK;

    nerf_fused<<<grid, BLOCK, 0, stream>>>(origins, directions, nearp, farp,
                                           W1, b1, W2, b2, out, B);
}